// Round 5
// baseline (860.514 us; speedup 1.0000x reference)
//
#include <hip/hip_runtime.h>
#include <hip/hip_bf16.h>

#define EPSF 1e-8f

typedef __attribute__((ext_vector_type(8))) __bf16 bf16x8;
typedef __attribute__((ext_vector_type(4))) float f32x4;

constexpr int S = 256;
constexpr int NB = 128;
constexpr int D2 = 512;
constexpr int HALF = 256;
constexpr int NBD2 = NB * D2;
constexpr size_t NORM_ELEMS = (size_t)2 * 33 * NB * S;  // per tensor (p or q)

// ws byte offsets
constexpr size_t OFF_ASUM  = 17301504;   // f32 [2*128*256]
constexpr size_t OFF_AIDX  = 17563648;   // i32 [2*128*256]
constexpr size_t OFF_QHI   = 17825792;   // bf16 [2*128][256 t][256 d]
constexpr size_t OFF_QLO   = 51380224;   // bf16 same
constexpr size_t OFF_QT    = 84934656;   // bf16 [2*128][256 d][256 t]
constexpr size_t OFF_ALPHA = 118489088;  // bf16 [2*128][256 s][256 t]
constexpr size_t WS_NEED   = 152043520;

__device__ __forceinline__ size_t normIdx(int dir, int slot, int b, int row) {
    return (((size_t)dir * 33 + slot) * NB + b) * S + row;
}

__device__ __forceinline__ uint pack2bf(float a, float b) {
    __hip_bfloat162 t = __float22bfloat162_rn(make_float2(a, b));
    uint u;
    __builtin_memcpy(&u, &t, 4);
    return u;
}

__device__ __forceinline__ bf16x8 ld8(const __bf16* p8) {  // 2x ds_read_b64
    union { uint2 u[2]; bf16x8 v; } t;
    t.u[0] = *(const uint2*)p8;
    t.u[1] = *(const uint2*)(p8 + 4);
    return t.v;
}

__device__ __forceinline__ void st16_u2(__bf16* dst, uint4 v) {  // 16 B via 2x b64
    *(uint2*)dst = make_uint2(v.x, v.y);
    *(uint2*)(dst + 4) = make_uint2(v.z, v.w);
}

// ---------------------------------------------------------------------------
// K0: all weighted norms.  grid = 2(tensor) * 2(dir) * 128(b), block = 256
// ---------------------------------------------------------------------------
__global__ __launch_bounds__(256) void k_norms(const float* __restrict__ p,
                                               const float* __restrict__ q,
                                               const float* __restrict__ W,
                                               float* __restrict__ ws)
{
    int blk = blockIdx.x;
    int b = blk & 127;
    int dir = (blk >> 7) & 1;
    int tensor = blk >> 8;
    const float* x = tensor ? q : p;
    float* outN = ws + (size_t)tensor * NORM_ELEMS;

    __shared__ float W2[32][HALF];
    for (int e = threadIdx.x; e < 32 * HALF; e += 256) {
        int slot = e >> 8;
        int d = e & (HALF - 1);
        int wl = slot >> 3, l = slot & 7;
        int wi = (wl == 0) ? dir : (wl == 1) ? (2 + dir) : (wl == 2) ? 4 : 5;
        float w = W[(size_t)(wi * 8 + l) * HALF + d];
        W2[slot][d] = w * w;
    }
    __syncthreads();

    int row = threadIdx.x;
    const float* xr = x + ((size_t)row * NB + b) * D2 + dir * HALF;
    float acc[33];
#pragma unroll
    for (int i = 0; i < 33; i++) acc[i] = 0.f;
    for (int d4 = 0; d4 < HALF; d4 += 4) {
        float4 v = *(const float4*)(xr + d4);
        float xx = v.x * v.x, yy = v.y * v.y, zz = v.z * v.z, ww = v.w * v.w;
        acc[32] += xx + yy + zz + ww;
#pragma unroll
        for (int slot = 0; slot < 32; slot++) {
            acc[slot] += xx * W2[slot][d4] + yy * W2[slot][d4 + 1]
                       + zz * W2[slot][d4 + 2] + ww * W2[slot][d4 + 3];
        }
    }
#pragma unroll
    for (int slot = 0; slot < 33; slot++)
        outN[normIdx(dir, slot, b, row)] = sqrtf(acc[slot]);
}

// ---------------------------------------------------------------------------
// K_packA: Qhi = rne_bf16(q), Qlo = rne_bf16(q - Qhi). grid 1024.
// ---------------------------------------------------------------------------
__global__ __launch_bounds__(256) void k_packA(const float* __restrict__ q,
                                               char* __restrict__ wsb)
{
    int blk = blockIdx.x;            // dir*512 + b*4 + tt
    int tt = blk & 3;
    int b = (blk >> 2) & 127;
    int dir = blk >> 9;
    int tid = threadIdx.x;
    int t = tt * 64 + (tid >> 2);
    int dpart = (tid & 3) * 64;
    const float* src = q + ((size_t)t * NB + b) * D2 + dir * HALF + dpart;
    size_t so = (((size_t)(dir * 128 + b)) << 16) + (size_t)t * 256 + dpart;
    __bf16* qhi = (__bf16*)(wsb + OFF_QHI) + so;
    __bf16* qlo = (__bf16*)(wsb + OFF_QLO) + so;
#pragma unroll
    for (int j = 0; j < 64; j += 8) {
        float4 v0 = *(const float4*)(src + j);
        float4 v1 = *(const float4*)(src + j + 4);
        uint h0 = pack2bf(v0.x, v0.y), h1 = pack2bf(v0.z, v0.w);
        uint h2 = pack2bf(v1.x, v1.y), h3 = pack2bf(v1.z, v1.w);
        *(uint4*)(qhi + j) = make_uint4(h0, h1, h2, h3);
        uint l0 = pack2bf(v0.x - __uint_as_float(h0 << 16),
                          v0.y - __uint_as_float(h0 & 0xffff0000u));
        uint l1 = pack2bf(v0.z - __uint_as_float(h1 << 16),
                          v0.w - __uint_as_float(h1 & 0xffff0000u));
        uint l2 = pack2bf(v1.x - __uint_as_float(h2 << 16),
                          v1.y - __uint_as_float(h2 & 0xffff0000u));
        uint l3 = pack2bf(v1.z - __uint_as_float(h3 << 16),
                          v1.w - __uint_as_float(h3 & 0xffff0000u));
        *(uint4*)(qlo + j) = make_uint4(l0, l1, l2, l3);
    }
}

// ---------------------------------------------------------------------------
// K_packT: QT[d][t] = Qhi[t][d] per (dir,b) slice. grid 256.
// ---------------------------------------------------------------------------
__global__ __launch_bounds__(256) void k_packT(char* __restrict__ wsb)
{
    int blk = blockIdx.x;  // dir*128+b
    const __bf16* qhi = (const __bf16*)(wsb + OFF_QHI) + ((size_t)blk << 16);
    __bf16* qt = (__bf16*)(wsb + OFF_QT) + ((size_t)blk << 16);
    __shared__ __align__(16) __bf16 tile[64 * 264];  // [d][t], stride 264
    int tid = threadIdx.x;
    for (int dt = 0; dt < 4; dt++) {
        {
            const __bf16* srow = qhi + (size_t)tid * 256 + dt * 64;
#pragma unroll
            for (int j0 = 0; j0 < 64; j0 += 8) {
                union { uint4 u; __bf16 h[8]; } v;
                v.u = *(const uint4*)(srow + j0);
#pragma unroll
                for (int j = 0; j < 8; j++) tile[(j0 + j) * 264 + tid] = v.h[j];
            }
        }
        __syncthreads();
        {
            int d = tid >> 2, tq = tid & 3;
            const uint4* srcl = (const uint4*)&tile[d * 264 + tq * 64];
            uint4* dst = (uint4*)(qt + (size_t)(dt * 64 + d) * 256 + tq * 64);
#pragma unroll
            for (int j = 0; j < 8; j++) dst[j] = srcl[j];
        }
        __syncthreads();
    }
}

// ---------------------------------------------------------------------------
// K1: m_full (out 0..15). Unchanged (passing).
// ---------------------------------------------------------------------------
__global__ __launch_bounds__(256) void k_full(const float* __restrict__ p,
                                              const float* __restrict__ q,
                                              const float* __restrict__ W,
                                              const float* __restrict__ ws,
                                              float* __restrict__ out)
{
    int blk = blockIdx.x;
    int bg = blk & 3;
    int s = (blk >> 2) & 255;
    int dir = blk >> 10;
    int tid = threadIdx.x;
    int b = bg * 32 + (tid >> 3);
    int l = tid & 7;
    int wi = dir;

    __shared__ float W2[8][HALF];
    for (int e = tid; e < 8 * HALF; e += 256) {
        int ll = e >> 8, d = e & (HALF - 1);
        float w = W[(size_t)(wi * 8 + ll) * HALF + d];
        W2[ll][d] = w * w;
    }
    __syncthreads();

    int qrow = dir ? 0 : (S - 1);
    const float* pr = p + ((size_t)s * NB + b) * D2 + dir * HALF;
    const float* qr = q + ((size_t)qrow * NB + b) * D2 + dir * HALF;
    float num = 0.f;
    for (int d4 = 0; d4 < HALF; d4 += 4) {
        float4 pv = *(const float4*)(pr + d4);
        float4 qv = *(const float4*)(qr + d4);
        num += pv.x * qv.x * W2[l][d4] + pv.y * qv.y * W2[l][d4 + 1]
             + pv.z * qv.z * W2[l][d4 + 2] + pv.w * qv.w * W2[l][d4 + 3];
    }
    const float* normP = ws;
    const float* normQ = ws + NORM_ELEMS;
    float n1 = normP[normIdx(dir, l, b, s)];
    float n2 = normQ[normIdx(dir, l, b, qrow)];
    out[((size_t)s * NB + b) * 64 + dir * 8 + l] = num / fmaxf(n1 * n2, EPSF);
}

// ---------------------------------------------------------------------------
// K2: maxpool, bf16 MFMA, ONE l per block (64 AGPR acc) for occupancy.
// grid 8192: grp = blk&255 -> (dir,b); sub = blk>>8: l = sub>>2, sc = sub&3.
// ---------------------------------------------------------------------------
__global__ __launch_bounds__(256, 3) void k_maxpool5(const float* __restrict__ p,
                                                     const float* __restrict__ W,
                                                     const char* __restrict__ wsb,
                                                     float* __restrict__ out)
{
    int grp = blockIdx.x & 255;
    int sub = blockIdx.x >> 8;
    int b = grp & 127, dir = grp >> 7;
    int l = sub >> 2, sc = sub & 3;
    int s0 = sc * 64;
    int wi = 2 + dir;
    int tid = threadIdx.x;

    __shared__ __align__(16) __bf16 Al[64][36];   // stride 72 B: conflict-light b64
    __shared__ __align__(16) __bf16 Bl[256][36];
    __shared__ __align__(16) float W2L[HALF];
    __shared__ float n1l[64];
    __shared__ float n2l[HALF];
    __shared__ float wmax[4][64];

    const float* normP = (const float*)wsb;
    const float* normQ = normP + NORM_ELEMS;
    const __bf16* qh = (const __bf16*)(wsb + OFF_QHI) + ((size_t)(dir * 128 + b) << 16);

    {
        float w = W[(size_t)(wi * 8 + l) * HALF + tid];
        W2L[tid] = w * w;
        n2l[tid] = normQ[normIdx(dir, 8 + l, b, tid)];
    }
    if (tid < 64) n1l[tid] = normP[normIdx(dir, 8 + l, b, s0 + tid)];

    int wave = tid >> 6, lane = tid & 63;
    int colq = lane & 15, quad = lane >> 4;
    int arow = tid >> 2, acg = (tid & 3) * 8;

    f32x4 acc[4][4];
#pragma unroll
    for (int mi = 0; mi < 4; mi++)
#pragma unroll
        for (int ni = 0; ni < 4; ni++)
#pragma unroll
            for (int k = 0; k < 4; k++) acc[mi][ni][k] = 0.f;

    const float* pbase = p + (size_t)b * D2 + dir * HALF;

    // small prefetch: Qhi chunk only (16 VGPR)
    uint4 breg[4];
    {
        const uint4* src = (const uint4*)(qh + (size_t)tid * 256);
        breg[0] = src[0]; breg[1] = src[1]; breg[2] = src[2]; breg[3] = src[3];
    }

    for (int kc = 0; kc < 8; kc++) {
        int k0 = kc * 32;
        __syncthreads();
        {
            __bf16* dst = &Bl[tid][0];
            st16_u2(dst, breg[0]); st16_u2(dst + 8, breg[1]);
            st16_u2(dst + 16, breg[2]); st16_u2(dst + 24, breg[3]);
        }
        {
            const float* pr = pbase + (size_t)(s0 + arow) * NBD2 + k0 + acg;
            float4 av0 = *(const float4*)pr;
            float4 av1 = *(const float4*)(pr + 4);
            float4 w0 = *(const float4*)&W2L[k0 + acg];
            float4 w1 = *(const float4*)&W2L[k0 + acg + 4];
            uint u0 = pack2bf(av0.x * w0.x, av0.y * w0.y);
            uint u1 = pack2bf(av0.z * w0.z, av0.w * w0.w);
            uint u2 = pack2bf(av1.x * w1.x, av1.y * w1.y);
            uint u3 = pack2bf(av1.z * w1.z, av1.w * w1.w);
            st16_u2(&Al[arow][acg], make_uint4(u0, u1, u2, u3));
        }
        __syncthreads();
        if (kc < 7) {
            const uint4* src = (const uint4*)(qh + (size_t)tid * 256 + k0 + 32);
            breg[0] = src[0]; breg[1] = src[1]; breg[2] = src[2]; breg[3] = src[3];
        }
        {
            int kk = quad * 8;
            bf16x8 bfr[4], afl[4];
#pragma unroll
            for (int ni = 0; ni < 4; ni++)
                bfr[ni] = ld8(&Bl[wave * 64 + ni * 16 + colq][kk]);
#pragma unroll
            for (int mi = 0; mi < 4; mi++)
                afl[mi] = ld8(&Al[mi * 16 + colq][kk]);
#pragma unroll
            for (int mi = 0; mi < 4; mi++)
#pragma unroll
                for (int ni = 0; ni < 4; ni++)
                    acc[mi][ni] = __builtin_amdgcn_mfma_f32_16x16x32_bf16(
                        afl[mi], bfr[ni], acc[mi][ni], 0, 0, 0);
        }
    }

#pragma unroll
    for (int mi = 0; mi < 4; mi++) {
#pragma unroll
        for (int rg = 0; rg < 4; rg++) {
            int sl = mi * 16 + quad * 4 + rg;
            float n1v = n1l[sl];
            float m = -3.4e38f;
#pragma unroll
            for (int ni = 0; ni < 4; ni++) {
                int t = wave * 64 + ni * 16 + colq;
                float sim = acc[mi][ni][rg] / fmaxf(n1v * n2l[t], EPSF);
                m = fmaxf(m, sim);
            }
#pragma unroll
            for (int msk = 1; msk < 16; msk <<= 1)
                m = fmaxf(m, __shfl_xor(m, msk, 64));
            if (colq == 0) wmax[wave][sl] = m;
        }
    }
    __syncthreads();
    if (tid < 64) {
        float m = fmaxf(fmaxf(wmax[0][tid], wmax[1][tid]),
                        fmaxf(wmax[2][tid], wmax[3][tid]));
        out[((size_t)(s0 + tid) * NB + b) * 64 + 16 + dir * 8 + l] = m;
    }
}

// ---------------------------------------------------------------------------
// K_alpha: alpha = cos(p,q); split-bf16 (3 MFMAs). No reg double-pump.
// grid 1024.
// ---------------------------------------------------------------------------
__global__ __launch_bounds__(256, 3) void k_alpha(const float* __restrict__ p,
                                                  char* __restrict__ wsb)
{
    int blk = blockIdx.x;
    int grp = blk & 255;
    int st = blk >> 8;
    int b = grp & 127, dir = grp >> 7;
    int s0 = st * 64;
    int tid = threadIdx.x;
    int wave = tid >> 6, lane = tid & 63;
    int colq = lane & 15, quad = lane >> 4;

    const float* normP = (const float*)wsb;
    const float* normQ = normP + NORM_ELEMS;
    size_t slice = (size_t)(dir * 128 + b) << 16;
    const __bf16* qh = (const __bf16*)(wsb + OFF_QHI) + slice;
    const __bf16* ql = (const __bf16*)(wsb + OFF_QLO) + slice;
    __bf16* aW = (__bf16*)(wsb + OFF_ALPHA) + slice;
    float* asumW = (float*)(wsb + OFF_ASUM) + (size_t)(dir * 128 + b) * 256;
    int* aidxW = (int*)(wsb + OFF_AIDX) + (size_t)(dir * 128 + b) * 256;

    __shared__ __align__(16) __bf16 QhiL[256][36];
    __shared__ __align__(16) __bf16 QloL[256][36];
    __shared__ __align__(16) __bf16 PhiL[64][36];
    __shared__ __align__(16) __bf16 PloL[64][36];
    __shared__ float redS[4][64];
    __shared__ float redM[4][64];
    __shared__ int   redI[4][64];

    const float* pbase = p + (size_t)b * D2 + dir * HALF;
    int prow_ = tid >> 2, pcg = (tid & 3) * 8;

    f32x4 acc[4][4];
#pragma unroll
    for (int mi = 0; mi < 4; mi++)
#pragma unroll
        for (int ni = 0; ni < 4; ni++)
#pragma unroll
            for (int k = 0; k < 4; k++) acc[mi][ni][k] = 0.f;

    for (int kc = 0; kc < 8; kc++) {
        int k0 = kc * 32;
        __syncthreads();
        {
            const uint4* sh = (const uint4*)(qh + (size_t)tid * 256 + k0);
            const uint4* sl_ = (const uint4*)(ql + (size_t)tid * 256 + k0);
            __bf16* dh = &QhiL[tid][0];
            __bf16* dl = &QloL[tid][0];
#pragma unroll
            for (int j = 0; j < 4; j++) st16_u2(dh + 8 * j, sh[j]);
#pragma unroll
            for (int j = 0; j < 4; j++) st16_u2(dl + 8 * j, sl_[j]);
        }
        {
            const float* pr = pbase + (size_t)(s0 + prow_) * NBD2 + k0 + pcg;
            float4 pv0 = *(const float4*)pr;
            float4 pv1 = *(const float4*)(pr + 4);
            uint h0 = pack2bf(pv0.x, pv0.y), h1 = pack2bf(pv0.z, pv0.w);
            uint h2 = pack2bf(pv1.x, pv1.y), h3 = pack2bf(pv1.z, pv1.w);
            uint l0 = pack2bf(pv0.x - __uint_as_float(h0 << 16),
                              pv0.y - __uint_as_float(h0 & 0xffff0000u));
            uint l1 = pack2bf(pv0.z - __uint_as_float(h1 << 16),
                              pv0.w - __uint_as_float(h1 & 0xffff0000u));
            uint l2 = pack2bf(pv1.x - __uint_as_float(h2 << 16),
                              pv1.y - __uint_as_float(h2 & 0xffff0000u));
            uint l3 = pack2bf(pv1.z - __uint_as_float(h3 << 16),
                              pv1.w - __uint_as_float(h3 & 0xffff0000u));
            st16_u2(&PhiL[prow_][pcg], make_uint4(h0, h1, h2, h3));
            st16_u2(&PloL[prow_][pcg], make_uint4(l0, l1, l2, l3));
        }
        __syncthreads();
        {
            int kk = quad * 8;
#pragma unroll
            for (int mi = 0; mi < 4; mi++) {
                bf16x8 ah = ld8(&PhiL[mi * 16 + colq][kk]);
                bf16x8 al_ = ld8(&PloL[mi * 16 + colq][kk]);
#pragma unroll
                for (int ni = 0; ni < 4; ni++) {
                    bf16x8 bh = ld8(&QhiL[wave * 64 + ni * 16 + colq][kk]);
                    bf16x8 bl_ = ld8(&QloL[wave * 64 + ni * 16 + colq][kk]);
                    acc[mi][ni] = __builtin_amdgcn_mfma_f32_16x16x32_bf16(
                        ah, bh, acc[mi][ni], 0, 0, 0);
                    acc[mi][ni] = __builtin_amdgcn_mfma_f32_16x16x32_bf16(
                        ah, bl_, acc[mi][ni], 0, 0, 0);
                    acc[mi][ni] = __builtin_amdgcn_mfma_f32_16x16x32_bf16(
                        al_, bh, acc[mi][ni], 0, 0, 0);
                }
            }
        }
    }

    // normalize, write alpha bf16 to ws, reduce sum/argmax
    float nqv[4];
#pragma unroll
    for (int ni = 0; ni < 4; ni++)
        nqv[ni] = normQ[normIdx(dir, 32, b, wave * 64 + ni * 16 + colq)];

#pragma unroll
    for (int mi = 0; mi < 4; mi++) {
        int rowbase = mi * 16 + quad * 4;
        float npa[4];
#pragma unroll
        for (int rg = 0; rg < 4; rg++)
            npa[rg] = normP[normIdx(dir, 32, b, s0 + rowbase + rg)];
        float av[4][4];
#pragma unroll
        for (int ni = 0; ni < 4; ni++)
#pragma unroll
            for (int rg = 0; rg < 4; rg++)
                av[ni][rg] = acc[mi][ni][rg] / fmaxf(npa[rg] * nqv[ni], EPSF);
#pragma unroll
        for (int ni = 0; ni < 4; ni++)
#pragma unroll
            for (int rg = 0; rg < 4; rg++)
                aW[(size_t)(s0 + rowbase + rg) * 256 + wave * 64 + ni * 16 + colq] =
                    (__bf16)av[ni][rg];
#pragma unroll
        for (int rg = 0; rg < 4; rg++) {
            float sm = av[0][rg] + av[1][rg] + av[2][rg] + av[3][rg];
            float mx = av[0][rg];
            int ix = wave * 64 + colq;
#pragma unroll
            for (int ni = 1; ni < 4; ni++) {
                if (av[ni][rg] > mx) { mx = av[ni][rg]; ix = wave * 64 + ni * 16 + colq; }
            }
#pragma unroll
            for (int off = 1; off < 16; off <<= 1) {
                sm += __shfl_xor(sm, off, 64);
                float m2 = __shfl_xor(mx, off, 64);
                int i2 = __shfl_xor(ix, off, 64);
                if (m2 > mx || (m2 == mx && i2 < ix)) { mx = m2; ix = i2; }
            }
            if (colq == 0) {
                redS[wave][rowbase + rg] = sm;
                redM[wave][rowbase + rg] = mx;
                redI[wave][rowbase + rg] = ix;
            }
        }
    }
    __syncthreads();
    if (tid < 64) {
        float sm = redS[0][tid] + redS[1][tid] + redS[2][tid] + redS[3][tid];
        float mx = redM[0][tid];
        int ix = redI[0][tid];
#pragma unroll
        for (int w = 1; w < 4; w++) {
            float m2 = redM[w][tid];
            int i2 = redI[w][tid];
            if (m2 > mx || (m2 == mx && i2 < ix)) { mx = m2; ix = i2; }
        }
        asumW[s0 + tid] = sm;
        aidxW[s0 + tid] = ix;
    }
}

// ---------------------------------------------------------------------------
// K_hout: h = alpha . q (bf16 MFMA), then E-GEMM epilogue. grid 1024.
// ---------------------------------------------------------------------------
__global__ __launch_bounds__(256, 3) void k_hout(const float* __restrict__ p,
                                                 const float* __restrict__ W,
                                                 char* __restrict__ wsb,
                                                 float* __restrict__ out)
{
    int blk = blockIdx.x;
    int grp = blk & 255;
    int st = blk >> 8;
    int b = grp & 127, dir = grp >> 7;
    int s0 = st * 64;
    int tid = threadIdx.x;
    int wave = tid >> 6, lane = tid & 63;
    int colq = lane & 15, quad = lane >> 4;

    const float* normP = (const float*)wsb;
    const float* normQ = normP + NORM_ELEMS;
    size_t slice = (size_t)(dir * 128 + b) << 16;
    const __bf16* qh = (const __bf16*)(wsb + OFF_QHI) + slice;
    const __bf16* qt = (const __bf16*)(wsb + OFF_QT) + slice;
    const __bf16* aW = (const __bf16*)(wsb + OFF_ALPHA) + slice;
    const float* asumW = (const float*)(wsb + OFF_ASUM) + (size_t)(dir * 128 + b) * 256;
    const int* aidxW = (const int*)(wsb + OFF_AIDX) + (size_t)(dir * 128 + b) * 256;

    // union region: phase3 alphaA[64][68] + QTl[256][68] = 43520 B
    //               phase4 E[64][260] + W45[16][260] = 41600 B
    __shared__ __align__(16) char reg0[43520];
    __bf16* alphaA = (__bf16*)reg0;              // [64][68]
    __bf16* QTl = alphaA + 64 * 68;              // [256][68]
    __bf16* E = (__bf16*)reg0;                   // [64][260]
    __bf16* W45 = E + 64 * 260;                  // [16][260]
    __shared__ int   aidxL[64];
    __shared__ float asumL[64];

    if (tid < 64) { aidxL[tid] = aidxW[s0 + tid]; asumL[tid] = asumW[s0 + tid]; }

    const float* pbase = p + (size_t)b * D2 + dir * HALF;

    f32x4 acc[4][4];
#pragma unroll
    for (int mi = 0; mi < 4; mi++)
#pragma unroll
        for (int ni = 0; ni < 4; ni++)
#pragma unroll
            for (int k = 0; k < 4; k++) acc[mi][ni][k] = 0.f;

    // phase 3: h[s][d] = sum_t alpha[s][t] q[t][d]; K = t, 4 chunks of 64
    int arow = tid >> 2, acp = (tid & 3) * 16;
    for (int tc = 0; tc < 4; tc++) {
        __syncthreads();
        {
            const uint4* src = (const uint4*)(aW + (size_t)(s0 + arow) * 256 + tc * 64 + acp);
            __bf16* dst = &alphaA[arow * 68 + acp];
            st16_u2(dst, src[0]); st16_u2(dst + 8, src[1]);
            const uint4* sq = (const uint4*)(qt + (size_t)tid * 256 + tc * 64);
            __bf16* dq = &QTl[tid * 68];
#pragma unroll
            for (int j = 0; j < 8; j++) st16_u2(dq + j * 8, sq[j]);
        }
        __syncthreads();
#pragma unroll
        for (int step = 0; step < 2; step++) {
            int kk = step * 32 + quad * 8;
#pragma unroll
            for (int mi = 0; mi < 4; mi++) {
                bf16x8 af = ld8(&alphaA[(mi * 16 + colq) * 68 + kk]);
#pragma unroll
                for (int ni = 0; ni < 4; ni++) {
                    bf16x8 bfr = ld8(&QTl[(wave * 64 + ni * 16 + colq) * 68 + kk]);
                    acc[mi][ni] = __builtin_amdgcn_mfma_f32_16x16x32_bf16(
                        af, bfr, acc[mi][ni], 0, 0, 0);
                }
            }
        }
    }

    // epilogue: E-GEMMs vs [W4^2; W5^2]
    __syncthreads();
    {
        int n = tid >> 4, dblk = (tid & 15) * 16;
        int wrow = (n < 8) ? (4 * 8 + n) : (5 * 8 + (n - 8));
        const float* wr = W + (size_t)wrow * HALF + dblk;
        float4 a = *(const float4*)wr;
        float4 bq = *(const float4*)(wr + 4);
        float4 c = *(const float4*)(wr + 8);
        float4 d4 = *(const float4*)(wr + 12);
        uint u0 = pack2bf(a.x * a.x, a.y * a.y), u1 = pack2bf(a.z * a.z, a.w * a.w);
        uint u2 = pack2bf(bq.x * bq.x, bq.y * bq.y), u3 = pack2bf(bq.z * bq.z, bq.w * bq.w);
        uint u4 = pack2bf(c.x * c.x, c.y * c.y), u5 = pack2bf(c.z * c.z, c.w * c.w);
        uint u6 = pack2bf(d4.x * d4.x, d4.y * d4.y), u7 = pack2bf(d4.z * d4.z, d4.w * d4.w);
        __bf16* dst = &W45[n * 260 + dblk];
        st16_u2(dst, make_uint4(u0, u1, u2, u3));
        st16_u2(dst + 8, make_uint4(u4, u5, u6, u7));
    }

    f32x4 c1, c2, c3;
#pragma unroll
    for (int k = 0; k < 4; k++) { c1[k] = 0.f; c2[k] = 0.f; c3[k] = 0.f; }

    // E1 = p .* h
#pragma unroll
    for (int mi = 0; mi < 4; mi++)
#pragma unroll
        for (int rg = 0; rg < 4; rg++) {
            int sl = mi * 16 + quad * 4 + rg;
            const float* prow = pbase + (size_t)(s0 + sl) * NBD2;
#pragma unroll
            for (int ni = 0; ni < 4; ni++) {
                int d = wave * 64 + ni * 16 + colq;
                E[sl * 260 + d] = (__bf16)(prow[d] * acc[mi][ni][rg]);
            }
        }
    __syncthreads();
#pragma unroll
    for (int step = 0; step < 8; step++) {
        int kk = step * 32 + quad * 8;
        bf16x8 ea = ld8(&E[(wave * 16 + colq) * 260 + kk]);
        bf16x8 wb = ld8(&W45[colq * 260 + kk]);
        c1 = __builtin_amdgcn_mfma_f32_16x16x32_bf16(ea, wb, c1, 0, 0, 0);
    }
    __syncthreads();

    // E2 = h .* h
#pragma unroll
    for (int mi = 0; mi < 4; mi++)
#pragma unroll
        for (int rg = 0; rg < 4; rg++) {
            int sl = mi * 16 + quad * 4 + rg;
#pragma unroll
            for (int ni = 0; ni < 4; ni++) {
                int d = wave * 64 + ni * 16 + colq;
                float hv = acc[mi][ni][rg];
                E[sl * 260 + d] = (__bf16)(hv * hv);
            }
        }
    __syncthreads();
#pragma unroll
    for (int step = 0; step < 8; step++) {
        int kk = step * 32 + quad * 8;
        bf16x8 ea = ld8(&E[(wave * 16 + colq) * 260 + kk]);
        bf16x8 wb = ld8(&W45[colq * 260 + kk]);
        c2 = __builtin_amdgcn_mfma_f32_16x16x32_bf16(ea, wb, c2, 0, 0, 0);
    }
    __syncthreads();

    // E3 = p .* q[aidx]
#pragma unroll
    for (int mi = 0; mi < 4; mi++)
#pragma unroll
        for (int rg = 0; rg < 4; rg++) {
            int sl = mi * 16 + quad * 4 + rg;
            const float* prow = pbase + (size_t)(s0 + sl) * NBD2;
            const __bf16* qrow = qh + (size_t)aidxL[sl] * 256;
#pragma unroll
            for (int ni = 0; ni < 4; ni++) {
                int d = wave * 64 + ni * 16 + colq;
                E[sl * 260 + d] = (__bf16)(prow[d] * (float)qrow[d]);
            }
        }
    __syncthreads();
#pragma unroll
    for (int step = 0; step < 8; step++) {
        int kk = step * 32 + quad * 8;
        bf16x8 ea = ld8(&E[(wave * 16 + colq) * 260 + kk]);
        bf16x8 wb = ld8(&W45[colq * 260 + kk]);
        c3 = __builtin_amdgcn_mfma_f32_16x16x32_bf16(ea, wb, c3, 0, 0, 0);
    }

    // write out: rows s = wave*16 + quad*4 + rg, col n = colq
#pragma unroll
    for (int rg = 0; rg < 4; rg++) {
        int sl = wave * 16 + quad * 4 + rg;
        size_t ob = ((size_t)(s0 + sl) * NB + b) * 64;
        if (colq < 8) {
            int l = colq;
            float np4 = normP[normIdx(dir, 16 + l, b, s0 + sl)];
            float nh = sqrtf(fmaxf(c2[rg], 0.f));
            float sgn = (asumL[sl] < 0.f) ? -1.f : 1.f;
            out[ob + 32 + dir * 8 + l] = sgn * c1[rg] / fmaxf(np4 * nh, EPSF);
        } else {
            int l = colq - 8;
            float np5 = normP[normIdx(dir, 24 + l, b, s0 + sl)];
            float nq5 = normQ[normIdx(dir, 24 + l, b, aidxL[sl])];
            out[ob + 48 + dir * 8 + l] = c3[rg] / fmaxf(np5 * nq5, EPSF);
        }
    }
}

// ---------------------------------------------------------------------------
extern "C" void kernel_launch(void* const* d_in, const int* in_sizes, int n_in,
                              void* d_out, int out_size, void* d_ws, size_t ws_size,
                              hipStream_t stream)
{
    (void)in_sizes; (void)n_in; (void)out_size;
    if (ws_size < WS_NEED) return;
    const float* p = (const float*)d_in[0];
    const float* q = (const float*)d_in[1];
    const float* W = (const float*)d_in[2];
    float* out = (float*)d_out;
    float* ws = (float*)d_ws;
    char* wsb = (char*)d_ws;

    hipLaunchKernelGGL(k_norms, dim3(512), dim3(256), 0, stream, p, q, W, ws);
    hipLaunchKernelGGL(k_packA, dim3(1024), dim3(256), 0, stream, q, wsb);
    hipLaunchKernelGGL(k_packT, dim3(256), dim3(256), 0, stream, wsb);
    hipLaunchKernelGGL(k_full, dim3(2048), dim3(256), 0, stream, p, q, W, ws, out);
    hipLaunchKernelGGL(k_maxpool5, dim3(8192), dim3(256), 0, stream, p, W, wsb, out);
    hipLaunchKernelGGL(k_alpha, dim3(1024), dim3(256), 0, stream, p, wsb);
    hipLaunchKernelGGL(k_hout, dim3(1024), dim3(256), 0, stream, p, W, wsb, out);
}